// Round 2
// baseline (542.329 us; speedup 1.0000x reference)
//
#include <hip/hip_runtime.h>
#include <math.h>

#define N_ENT 4096
#define BATCH 4
#define NHID  3
#define EMB   64
#define ALPHA 0.2f
#define MASK_FILL 9e-15f

// ---------------------------------------------------------------------------
// Kernel 1: h = ent_emb @ W  [4096,3]; src = h@a[:3]; dst = h@a[3:]
// ---------------------------------------------------------------------------
__global__ __launch_bounds__(256) void prep_kernel(
    const float* __restrict__ emb, const float* __restrict__ W,
    const float* __restrict__ a,
    float* __restrict__ h0G, float* __restrict__ h1G, float* __restrict__ h2G,
    float* __restrict__ dstG, float* __restrict__ srcG)
{
    int j = blockIdx.x * 256 + threadIdx.x;
    if (j >= N_ENT) return;
    const float* er = emb + (size_t)j * EMB;
    float h0 = 0.f, h1 = 0.f, h2 = 0.f;
    #pragma unroll
    for (int e = 0; e < EMB; ++e) {
        float v = er[e];
        h0 += v * W[e * 3 + 0];
        h1 += v * W[e * 3 + 1];
        h2 += v * W[e * 3 + 2];
    }
    h0G[j] = h0; h1G[j] = h1; h2G[j] = h2;
    srcG[j] = h0 * a[0] + h1 * a[1] + h2 * a[2];
    dstG[j] = h0 * a[3] + h1 * a[4] + h2 * a[5];
}

// ---------------------------------------------------------------------------
// Kernel 2: per (b,i) row. One wave per row.
//   m   = max(edge? lrelu(src+max_edge dst) , nonedge? MASK_FILL)
//         (valid because leakyrelu is monotone — no logit array needed)
//   w_j = adj ? exp(lrelu(src+dst_j)-m) : exp(MASK_FILL-m)   (branchless)
//   h'  = (sum w_j * h_j) / (sum w_j);  ELU.
// No per-element state survives between passes except av[16] (64 VGPRs) ->
// no scratch spill (R1 failure mode: vals[64]+av[16]=128 VGPRs spilled 536MB).
// ---------------------------------------------------------------------------
__global__ __launch_bounds__(256, 2) void gat_row_kernel(
    const int* __restrict__ adj,
    const float* __restrict__ h0G, const float* __restrict__ h1G,
    const float* __restrict__ h2G, const float* __restrict__ dstG,
    const float* __restrict__ srcG, float* __restrict__ xG)
{
    __shared__ float dstL[N_ENT];
    __shared__ float h0L[N_ENT];
    __shared__ float h1L[N_ENT];
    __shared__ float h2L[N_ENT];

    int tid = threadIdx.x;
    for (int t = tid; t < N_ENT; t += 256) {
        dstL[t] = dstG[t];
        h0L[t]  = h0G[t];
        h1L[t]  = h1G[t];
        h2L[t]  = h2G[t];
    }
    __syncthreads();

    int lane = tid & 63;
    int gw   = blockIdx.x * 4 + (tid >> 6);   // global wave id, 0..2047

    for (int r = 0; r < 8; ++r) {
        int row = gw * 8 + r;                 // row = b*N_ENT + i, 0..16383
        int i   = row & (N_ENT - 1);
        float src = srcG[i];
        const int4* arow = (const int4*)(adj + (size_t)row * N_ENT);

        // ---- issue all 16 adjacency int4 loads up-front (MLP) ----
        int4 av[16];
        #pragma unroll
        for (int c = 0; c < 16; ++c) av[c] = arow[c * 64 + lane];

        // ---- pass A: masked max of dst over edges + any-non-edge flag ----
        float md = -3.4e38f;
        int   mn = 2;                         // min over adj values
        #pragma unroll
        for (int c = 0; c < 16; ++c) {
            int jb = (c * 64 + lane) * 4;
            float4 d4 = *(const float4*)&dstL[jb];
            md = fmaxf(md, av[c].x > 0 ? d4.x : -3.4e38f);
            md = fmaxf(md, av[c].y > 0 ? d4.y : -3.4e38f);
            md = fmaxf(md, av[c].z > 0 ? d4.z : -3.4e38f);
            md = fmaxf(md, av[c].w > 0 ? d4.w : -3.4e38f);
            mn = min(mn, min(min(av[c].x, av[c].y), min(av[c].z, av[c].w)));
        }
        #pragma unroll
        for (int off = 32; off; off >>= 1) {
            md = fmaxf(md, __shfl_xor(md, off, 64));
            mn = min(mn, __shfl_xor(mn, off, 64));
        }
        float tm = src + md;
        float m  = (md > -1e38f) ? fmaxf(tm, ALPHA * tm) : -3.4e38f;
        if (mn <= 0) m = fmaxf(m, MASK_FILL);
        float C = __expf(MASK_FILL - m);      // shared weight of every non-edge

        // ---- pass B: branchless weighted accumulation ----
        float l = 0.f, n0 = 0.f, n1 = 0.f, n2 = 0.f;
        #pragma unroll
        for (int c = 0; c < 16; ++c) {
            int jb = (c * 64 + lane) * 4;
            float4 d4 = *(const float4*)&dstL[jb];
            float4 a0 = *(const float4*)&h0L[jb];
            float4 a1 = *(const float4*)&h1L[jb];
            float4 a2 = *(const float4*)&h2L[jb];
            float t0 = src + d4.x, t1 = src + d4.y, t2 = src + d4.z, t3 = src + d4.w;
            float e0 = __expf(fmaxf(t0, ALPHA * t0) - m);
            float e1 = __expf(fmaxf(t1, ALPHA * t1) - m);
            float e2 = __expf(fmaxf(t2, ALPHA * t2) - m);
            float e3 = __expf(fmaxf(t3, ALPHA * t3) - m);
            float w0 = av[c].x > 0 ? e0 : C;
            float w1 = av[c].y > 0 ? e1 : C;
            float w2 = av[c].z > 0 ? e2 : C;
            float w3 = av[c].w > 0 ? e3 : C;
            l  += (w0 + w1) + (w2 + w3);
            n0 += w0 * a0.x + w1 * a0.y + w2 * a0.z + w3 * a0.w;
            n1 += w0 * a1.x + w1 * a1.y + w2 * a1.z + w3 * a1.w;
            n2 += w0 * a2.x + w1 * a2.y + w2 * a2.z + w3 * a2.w;
        }
        #pragma unroll
        for (int off = 32; off; off >>= 1) {
            l  += __shfl_xor(l,  off, 64);
            n0 += __shfl_xor(n0, off, 64);
            n1 += __shfl_xor(n1, off, 64);
            n2 += __shfl_xor(n2, off, 64);
        }

        if (lane == 0) {
            float inv = 1.f / l;
            float hp0 = n0 * inv, hp1 = n1 * inv, hp2 = n2 * inv;
            float* xp = xG + (size_t)row * 3;
            xp[0] = hp0 > 0.f ? hp0 : expm1f(hp0);   // ELU (alpha=1)
            xp[1] = hp1 > 0.f ? hp1 : expm1f(hp1);
            xp[2] = hp2 > 0.f ? hp2 : expm1f(hp2);
        }
    }
}

// ---------------------------------------------------------------------------
// Kernel 3: out[b,k] = x[b,:] . fc1_w[k,:] + fc1_b[k].  One block per k,
// 4 batch accumulators so each weight row is read once.
// ---------------------------------------------------------------------------
__global__ __launch_bounds__(256) void fc_kernel(
    const float* __restrict__ xG, const float* __restrict__ w,
    const float* __restrict__ bias, float* __restrict__ out)
{
    int k   = blockIdx.x;           // 0..99
    int tid = threadIdx.x;
    const float4* wr = (const float4*)(w + (size_t)k * (N_ENT * NHID));
    const float4* x0 = (const float4*)(xG + 0 * (N_ENT * NHID));
    const float4* x1 = (const float4*)(xG + 1 * (N_ENT * NHID));
    const float4* x2 = (const float4*)(xG + 2 * (N_ENT * NHID));
    const float4* x3 = (const float4*)(xG + 3 * (N_ENT * NHID));

    float acc0 = 0.f, acc1 = 0.f, acc2 = 0.f, acc3 = 0.f;
    for (int t = tid; t < (N_ENT * NHID / 4); t += 256) {   // 3072/256 = 12 iters
        float4 wv = wr[t];
        float4 xv;
        xv = x0[t]; acc0 += wv.x*xv.x + wv.y*xv.y + wv.z*xv.z + wv.w*xv.w;
        xv = x1[t]; acc1 += wv.x*xv.x + wv.y*xv.y + wv.z*xv.z + wv.w*xv.w;
        xv = x2[t]; acc2 += wv.x*xv.x + wv.y*xv.y + wv.z*xv.z + wv.w*xv.w;
        xv = x3[t]; acc3 += wv.x*xv.x + wv.y*xv.y + wv.z*xv.z + wv.w*xv.w;
    }

    #pragma unroll
    for (int off = 32; off; off >>= 1) {
        acc0 += __shfl_xor(acc0, off, 64);
        acc1 += __shfl_xor(acc1, off, 64);
        acc2 += __shfl_xor(acc2, off, 64);
        acc3 += __shfl_xor(acc3, off, 64);
    }

    __shared__ float red[4][4];     // [wave][batch]
    int lane = tid & 63, wv_ = tid >> 6;
    if (lane == 0) {
        red[wv_][0] = acc0; red[wv_][1] = acc1;
        red[wv_][2] = acc2; red[wv_][3] = acc3;
    }
    __syncthreads();
    if (tid < 4) {   // tid = batch index
        float s = red[0][tid] + red[1][tid] + red[2][tid] + red[3][tid] + bias[k];
        out[tid * 100 + k] = s;
    }
}

// ---------------------------------------------------------------------------
extern "C" void kernel_launch(void* const* d_in, const int* in_sizes, int n_in,
                              void* d_out, int out_size, void* d_ws, size_t ws_size,
                              hipStream_t stream)
{
    const int*   adj  = (const int*)d_in[0];
    const float* emb  = (const float*)d_in[1];
    const float* W    = (const float*)d_in[2];
    const float* a    = (const float*)d_in[3];
    const float* fc1w = (const float*)d_in[4];
    const float* fc1b = (const float*)d_in[5];
    float* out = (float*)d_out;

    float* ws   = (float*)d_ws;
    float* h0G  = ws;               // 4096
    float* h1G  = ws + 4096;        // 4096
    float* h2G  = ws + 8192;        // 4096
    float* dstG = ws + 12288;       // 4096
    float* srcG = ws + 16384;       // 4096
    float* xG   = ws + 20480;       // 4*4096*3 = 49152

    prep_kernel<<<N_ENT / 256, 256, 0, stream>>>(emb, W, a, h0G, h1G, h2G, dstG, srcG);
    gat_row_kernel<<<512, 256, 0, stream>>>(adj, h0G, h1G, h2G, dstG, srcG, xG);
    fc_kernel<<<100, 256, 0, stream>>>(xG, fc1w, fc1b, out);
}

// Round 3
// 410.026 us; speedup vs baseline: 1.3227x; 1.3227x over previous
//
#include <hip/hip_runtime.h>
#include <math.h>

#define N_ENT 4096
#define BATCH 4
#define NHID  3
#define EMB   64
#define ALPHA 0.2f
#define MASK_FILL 9e-15f

// ---------------------------------------------------------------------------
// Kernel 1: h = ent_emb @ W  [4096,3]; src = h@a[:3]; dst = h@a[3:]
// ---------------------------------------------------------------------------
__global__ __launch_bounds__(256) void prep_kernel(
    const float* __restrict__ emb, const float* __restrict__ W,
    const float* __restrict__ a,
    float* __restrict__ h0G, float* __restrict__ h1G, float* __restrict__ h2G,
    float* __restrict__ dstG, float* __restrict__ srcG)
{
    int j = blockIdx.x * 256 + threadIdx.x;
    if (j >= N_ENT) return;
    const float* er = emb + (size_t)j * EMB;
    float h0 = 0.f, h1 = 0.f, h2 = 0.f;
    #pragma unroll
    for (int e = 0; e < EMB; ++e) {
        float v = er[e];
        h0 += v * W[e * 3 + 0];
        h1 += v * W[e * 3 + 1];
        h2 += v * W[e * 3 + 2];
    }
    h0G[j] = h0; h1G[j] = h1; h2G[j] = h2;
    srcG[j] = h0 * a[0] + h1 * a[1] + h2 * a[2];
    dstG[j] = h0 * a[3] + h1 * a[4] + h2 * a[5];
}

// ---------------------------------------------------------------------------
// Kernel 2: per (b,i) row, one wave per row, SINGLE PASS online softmax.
// Per lane running (m, l, n0..n2); branchless rescale by exp(m_old - m_new)
// per 4-element chunk; butterfly shuffle merge at the end.
// adj read exactly once; no per-element register arrays -> no scratch spill
// (R1 spilled vals[64]; R2 spilled av[16] across two passes: 103MB scratch).
// ---------------------------------------------------------------------------
__global__ __launch_bounds__(256, 2) void gat_row_kernel(
    const int* __restrict__ adj,
    const float* __restrict__ h0G, const float* __restrict__ h1G,
    const float* __restrict__ h2G, const float* __restrict__ dstG,
    const float* __restrict__ srcG, float* __restrict__ xG)
{
    __shared__ float dstL[N_ENT];
    __shared__ float h0L[N_ENT];
    __shared__ float h1L[N_ENT];
    __shared__ float h2L[N_ENT];

    int tid = threadIdx.x;
    for (int t = tid; t < N_ENT; t += 256) {
        dstL[t] = dstG[t];
        h0L[t]  = h0G[t];
        h1L[t]  = h1G[t];
        h2L[t]  = h2G[t];
    }
    __syncthreads();

    int lane = tid & 63;
    int gw   = blockIdx.x * 4 + (tid >> 6);   // global wave id, 0..2047

    for (int r = 0; r < 8; ++r) {
        int row = gw * 8 + r;                 // row = b*N_ENT + i, 0..16383
        int i   = row & (N_ENT - 1);
        float src = srcG[i];
        const int4* arow = (const int4*)(adj + (size_t)row * N_ENT);

        float m = -3.4e38f, l = 0.f, n0 = 0.f, n1 = 0.f, n2 = 0.f;

        // unroll 4: up to 4 outstanding int4 loads (16 VGPRs), no spill
        #pragma unroll 4
        for (int c = 0; c < 16; ++c) {
            int4 av = arow[c * 64 + lane];
            int jb = (c * 64 + lane) * 4;
            float4 d4 = *(const float4*)&dstL[jb];

            float t0 = src + d4.x, t1 = src + d4.y, t2 = src + d4.z, t3 = src + d4.w;
            float v0 = av.x > 0 ? fmaxf(t0, ALPHA * t0) : MASK_FILL;
            float v1 = av.y > 0 ? fmaxf(t1, ALPHA * t1) : MASK_FILL;
            float v2 = av.z > 0 ? fmaxf(t2, ALPHA * t2) : MASK_FILL;
            float v3 = av.w > 0 ? fmaxf(t3, ALPHA * t3) : MASK_FILL;

            // branchless online-softmax rescale
            float m4 = fmaxf(fmaxf(v0, v1), fmaxf(v2, v3));
            float mn = fmaxf(m, m4);
            float s  = __expf(m - mn);        // ==1 when m unchanged
            l *= s; n0 *= s; n1 *= s; n2 *= s;
            m = mn;

            float4 a0 = *(const float4*)&h0L[jb];
            float4 a1 = *(const float4*)&h1L[jb];
            float4 a2 = *(const float4*)&h2L[jb];
            float p0 = __expf(v0 - m);
            float p1 = __expf(v1 - m);
            float p2 = __expf(v2 - m);
            float p3 = __expf(v3 - m);
            l  += (p0 + p1) + (p2 + p3);
            n0 += p0 * a0.x + p1 * a0.y + p2 * a0.z + p3 * a0.w;
            n1 += p0 * a1.x + p1 * a1.y + p2 * a1.z + p3 * a1.w;
            n2 += p0 * a2.x + p1 * a2.y + p2 * a2.z + p3 * a2.w;
        }

        // ---- butterfly merge of (m,l,n) across 64 lanes ----
        #pragma unroll
        for (int off = 32; off; off >>= 1) {
            float mo = __shfl_xor(m,  off, 64);
            float lo = __shfl_xor(l,  off, 64);
            float o0 = __shfl_xor(n0, off, 64);
            float o1 = __shfl_xor(n1, off, 64);
            float o2 = __shfl_xor(n2, off, 64);
            float mm = fmaxf(m, mo);
            float sa = __expf(m  - mm);
            float sb = __expf(mo - mm);
            l  = l  * sa + lo * sb;
            n0 = n0 * sa + o0 * sb;
            n1 = n1 * sa + o1 * sb;
            n2 = n2 * sa + o2 * sb;
            m  = mm;
        }

        if (lane == 0) {
            float inv = 1.f / l;
            float hp0 = n0 * inv, hp1 = n1 * inv, hp2 = n2 * inv;
            float* xp = xG + (size_t)row * 3;
            xp[0] = hp0 > 0.f ? hp0 : expm1f(hp0);   // ELU (alpha=1)
            xp[1] = hp1 > 0.f ? hp1 : expm1f(hp1);
            xp[2] = hp2 > 0.f ? hp2 : expm1f(hp2);
        }
    }
}

// ---------------------------------------------------------------------------
// Kernel 3: out[b,k] = x[b,:] . fc1_w[k,:] + fc1_b[k].  One block per k,
// 4 batch accumulators so each weight row is read once.
// ---------------------------------------------------------------------------
__global__ __launch_bounds__(256) void fc_kernel(
    const float* __restrict__ xG, const float* __restrict__ w,
    const float* __restrict__ bias, float* __restrict__ out)
{
    int k   = blockIdx.x;           // 0..99
    int tid = threadIdx.x;
    const float4* wr = (const float4*)(w + (size_t)k * (N_ENT * NHID));
    const float4* x0 = (const float4*)(xG + 0 * (N_ENT * NHID));
    const float4* x1 = (const float4*)(xG + 1 * (N_ENT * NHID));
    const float4* x2 = (const float4*)(xG + 2 * (N_ENT * NHID));
    const float4* x3 = (const float4*)(xG + 3 * (N_ENT * NHID));

    float acc0 = 0.f, acc1 = 0.f, acc2 = 0.f, acc3 = 0.f;
    for (int t = tid; t < (N_ENT * NHID / 4); t += 256) {   // 3072/256 = 12 iters
        float4 wv = wr[t];
        float4 xv;
        xv = x0[t]; acc0 += wv.x*xv.x + wv.y*xv.y + wv.z*xv.z + wv.w*xv.w;
        xv = x1[t]; acc1 += wv.x*xv.x + wv.y*xv.y + wv.z*xv.z + wv.w*xv.w;
        xv = x2[t]; acc2 += wv.x*xv.x + wv.y*xv.y + wv.z*xv.z + wv.w*xv.w;
        xv = x3[t]; acc3 += wv.x*xv.x + wv.y*xv.y + wv.z*xv.z + wv.w*xv.w;
    }

    #pragma unroll
    for (int off = 32; off; off >>= 1) {
        acc0 += __shfl_xor(acc0, off, 64);
        acc1 += __shfl_xor(acc1, off, 64);
        acc2 += __shfl_xor(acc2, off, 64);
        acc3 += __shfl_xor(acc3, off, 64);
    }

    __shared__ float red[4][4];     // [wave][batch]
    int lane = tid & 63, wv_ = tid >> 6;
    if (lane == 0) {
        red[wv_][0] = acc0; red[wv_][1] = acc1;
        red[wv_][2] = acc2; red[wv_][3] = acc3;
    }
    __syncthreads();
    if (tid < 4) {   // tid = batch index
        float s = red[0][tid] + red[1][tid] + red[2][tid] + red[3][tid] + bias[k];
        out[tid * 100 + k] = s;
    }
}

// ---------------------------------------------------------------------------
extern "C" void kernel_launch(void* const* d_in, const int* in_sizes, int n_in,
                              void* d_out, int out_size, void* d_ws, size_t ws_size,
                              hipStream_t stream)
{
    const int*   adj  = (const int*)d_in[0];
    const float* emb  = (const float*)d_in[1];
    const float* W    = (const float*)d_in[2];
    const float* a    = (const float*)d_in[3];
    const float* fc1w = (const float*)d_in[4];
    const float* fc1b = (const float*)d_in[5];
    float* out = (float*)d_out;

    float* ws   = (float*)d_ws;
    float* h0G  = ws;               // 4096
    float* h1G  = ws + 4096;        // 4096
    float* h2G  = ws + 8192;        // 4096
    float* dstG = ws + 12288;       // 4096
    float* srcG = ws + 16384;       // 4096
    float* xG   = ws + 20480;       // 4*4096*3 = 49152

    prep_kernel<<<N_ENT / 256, 256, 0, stream>>>(emb, W, a, h0G, h1G, h2G, dstG, srcG);
    gat_row_kernel<<<512, 256, 0, stream>>>(adj, h0G, h1G, h2G, dstG, srcG, xG);
    fc_kernel<<<100, 256, 0, stream>>>(xG, fc1w, fc1b, out);
}

// Round 4
// 383.790 us; speedup vs baseline: 1.4131x; 1.0684x over previous
//
#include <hip/hip_runtime.h>
#include <math.h>

#define N_ENT 4096
#define BATCH 4
#define NHID  3
#define EMB   64
#define ALPHA 0.2f
#define MASK_FILL 9e-15f
#define LOG2E 1.4426950408889634f
#define MASKP (MASK_FILL * LOG2E)

#if defined(__has_builtin)
#  if __has_builtin(__builtin_amdgcn_exp2f)
#    define EXP2F(x) __builtin_amdgcn_exp2f(x)
#  else
#    define EXP2F(x) exp2f(x)
#  endif
#else
#  define EXP2F(x) exp2f(x)
#endif

// ---------------------------------------------------------------------------
// Kernel 1: h = ent_emb @ W; dst' = (h@a[3:])*log2e; src' = (h@a[:3])*log2e.
// dst/src pre-scaled by log2e so the GAT inner loop uses raw v_exp_f32 (exp2).
// ---------------------------------------------------------------------------
__global__ __launch_bounds__(256) void prep_kernel(
    const float* __restrict__ emb, const float* __restrict__ W,
    const float* __restrict__ a,
    float* __restrict__ h0G, float* __restrict__ h1G, float* __restrict__ h2G,
    float* __restrict__ dstG, float* __restrict__ srcG)
{
    int j = blockIdx.x * 256 + threadIdx.x;
    if (j >= N_ENT) return;
    const float* er = emb + (size_t)j * EMB;
    float h0 = 0.f, h1 = 0.f, h2 = 0.f;
    #pragma unroll
    for (int e = 0; e < EMB; ++e) {
        float v = er[e];
        h0 += v * W[e * 3 + 0];
        h1 += v * W[e * 3 + 1];
        h2 += v * W[e * 3 + 2];
    }
    h0G[j] = h0; h1G[j] = h1; h2G[j] = h2;
    srcG[j] = (h0 * a[0] + h1 * a[1] + h2 * a[2]) * LOG2E;
    dstG[j] = (h0 * a[3] + h1 * a[4] + h2 * a[5]) * LOG2E;
}

// ---------------------------------------------------------------------------
// Kernel 2: per (b,i) row, one wave per 2 rows, FIXED-REFERENCE softmax.
// Softmax is shift-invariant: M_row = max(lrelu(src+maxd), MASK)*log2e is a
// guaranteed upper bound on every logit (lrelu monotone, maxd = max over ALL
// dst >= max over edges), so exp2(v-M) <= 1 (no overflow) and n/l is EXACT.
// No online rescale, no cross-chunk dependency, no register arrays.
// 1024-thread block, 64KB LDS, <=64 VGPR -> 2 blocks/CU = 32 waves/CU.
// ---------------------------------------------------------------------------
__global__ __launch_bounds__(1024, 8) void gat_row_kernel(
    const int* __restrict__ adj,
    const float* __restrict__ h0G, const float* __restrict__ h1G,
    const float* __restrict__ h2G, const float* __restrict__ dstG,
    const float* __restrict__ srcG, float* __restrict__ xG)
{
    __shared__ float dstL[N_ENT];   // SoA: float4 reads are bank-conflict-free
    __shared__ float h0L[N_ENT];
    __shared__ float h1L[N_ENT];
    __shared__ float h2L[N_ENT];
    __shared__ float maxdL[16];

    int tid  = threadIdx.x;
    int lane = tid & 63;
    int wid  = tid >> 6;            // 0..15

    float md = -3.4e38f;
    #pragma unroll
    for (int t = tid; t < N_ENT; t += 1024) {
        float dv = dstG[t];
        dstL[t] = dv;
        md = fmaxf(md, dv);
        h0L[t] = h0G[t];
        h1L[t] = h1G[t];
        h2L[t] = h2G[t];
    }
    // block-wide max of dst' (scaled domain)
    #pragma unroll
    for (int off = 32; off; off >>= 1) md = fmaxf(md, __shfl_xor(md, off, 64));
    if (lane == 0) maxdL[wid] = md;
    __syncthreads();
    float maxd = maxdL[0];
    #pragma unroll
    for (int t = 1; t < 16; ++t) maxd = fmaxf(maxd, maxdL[t]);

    int gw = blockIdx.x * 16 + wid;       // 0..8191

    for (int r = 0; r < 2; ++r) {
        int row = gw * 2 + r;             // 0..16383
        int i   = row & (N_ENT - 1);
        float srcp = srcG[i];             // scaled by log2e
        float t0 = srcp + maxd;
        float M  = fmaxf(fmaxf(t0, ALPHA * t0), (float)MASKP);  // >= all logits'
        float sA = srcp - M;
        float sB = ALPHA * srcp - M;
        float CM = EXP2F((float)MASKP - M);   // shared non-edge weight

        const int4* arow = (const int4*)(adj + (size_t)row * N_ENT);

        float l = 0.f, n0 = 0.f, n1 = 0.f, n2 = 0.f;
        #pragma unroll 1
        for (int c = 0; c < 16; ++c) {
            int4 av = arow[c * 64 + lane];
            int jb = (c * 64 + lane) * 4;
            float4 d4 = *(const float4*)&dstL[jb];
            float4 a0 = *(const float4*)&h0L[jb];
            float4 a1 = *(const float4*)&h1L[jb];
            float4 a2 = *(const float4*)&h2L[jb];
            // arg = lrelu(src+dst)*log2e - M, branch-free
            float g0 = EXP2F(fmaxf(sA + d4.x, fmaf(ALPHA, d4.x, sB)));
            float g1 = EXP2F(fmaxf(sA + d4.y, fmaf(ALPHA, d4.y, sB)));
            float g2 = EXP2F(fmaxf(sA + d4.z, fmaf(ALPHA, d4.z, sB)));
            float g3 = EXP2F(fmaxf(sA + d4.w, fmaf(ALPHA, d4.w, sB)));
            float w0 = av.x > 0 ? g0 : CM;
            float w1 = av.y > 0 ? g1 : CM;
            float w2 = av.z > 0 ? g2 : CM;
            float w3 = av.w > 0 ? g3 : CM;
            l  += (w0 + w1) + (w2 + w3);
            n0 = fmaf(w0, a0.x, fmaf(w1, a0.y, fmaf(w2, a0.z, fmaf(w3, a0.w, n0))));
            n1 = fmaf(w0, a1.x, fmaf(w1, a1.y, fmaf(w2, a1.z, fmaf(w3, a1.w, n1))));
            n2 = fmaf(w0, a2.x, fmaf(w1, a2.y, fmaf(w2, a2.z, fmaf(w3, a2.w, n2))));
        }

        #pragma unroll
        for (int off = 32; off; off >>= 1) {
            l  += __shfl_xor(l,  off, 64);
            n0 += __shfl_xor(n0, off, 64);
            n1 += __shfl_xor(n1, off, 64);
            n2 += __shfl_xor(n2, off, 64);
        }

        if (lane == 0) {
            float inv = 1.f / l;
            float hp0 = n0 * inv, hp1 = n1 * inv, hp2 = n2 * inv;
            float* xp = xG + (size_t)row * 3;
            xp[0] = hp0 > 0.f ? hp0 : expm1f(hp0);   // ELU (alpha=1)
            xp[1] = hp1 > 0.f ? hp1 : expm1f(hp1);
            xp[2] = hp2 > 0.f ? hp2 : expm1f(hp2);
        }
    }
}

// ---------------------------------------------------------------------------
// Kernel 3: out[b,k] = x[b,:] . fc1_w[k,:] + fc1_b[k].
// ---------------------------------------------------------------------------
__global__ __launch_bounds__(256) void fc_kernel(
    const float* __restrict__ xG, const float* __restrict__ w,
    const float* __restrict__ bias, float* __restrict__ out)
{
    int k   = blockIdx.x;           // 0..99
    int tid = threadIdx.x;
    const float4* wr = (const float4*)(w + (size_t)k * (N_ENT * NHID));
    const float4* x0 = (const float4*)(xG + 0 * (N_ENT * NHID));
    const float4* x1 = (const float4*)(xG + 1 * (N_ENT * NHID));
    const float4* x2 = (const float4*)(xG + 2 * (N_ENT * NHID));
    const float4* x3 = (const float4*)(xG + 3 * (N_ENT * NHID));

    float acc0 = 0.f, acc1 = 0.f, acc2 = 0.f, acc3 = 0.f;
    for (int t = tid; t < (N_ENT * NHID / 4); t += 256) {
        float4 wv = wr[t];
        float4 xv;
        xv = x0[t]; acc0 += wv.x*xv.x + wv.y*xv.y + wv.z*xv.z + wv.w*xv.w;
        xv = x1[t]; acc1 += wv.x*xv.x + wv.y*xv.y + wv.z*xv.z + wv.w*xv.w;
        xv = x2[t]; acc2 += wv.x*xv.x + wv.y*xv.y + wv.z*xv.z + wv.w*xv.w;
        xv = x3[t]; acc3 += wv.x*xv.x + wv.y*xv.y + wv.z*xv.z + wv.w*xv.w;
    }

    #pragma unroll
    for (int off = 32; off; off >>= 1) {
        acc0 += __shfl_xor(acc0, off, 64);
        acc1 += __shfl_xor(acc1, off, 64);
        acc2 += __shfl_xor(acc2, off, 64);
        acc3 += __shfl_xor(acc3, off, 64);
    }

    __shared__ float red[4][4];
    int lane = tid & 63, wv_ = tid >> 6;
    if (lane == 0) {
        red[wv_][0] = acc0; red[wv_][1] = acc1;
        red[wv_][2] = acc2; red[wv_][3] = acc3;
    }
    __syncthreads();
    if (tid < 4) {
        float s = red[0][tid] + red[1][tid] + red[2][tid] + red[3][tid] + bias[k];
        out[tid * 100 + k] = s;
    }
}

// ---------------------------------------------------------------------------
extern "C" void kernel_launch(void* const* d_in, const int* in_sizes, int n_in,
                              void* d_out, int out_size, void* d_ws, size_t ws_size,
                              hipStream_t stream)
{
    const int*   adj  = (const int*)d_in[0];
    const float* emb  = (const float*)d_in[1];
    const float* W    = (const float*)d_in[2];
    const float* a    = (const float*)d_in[3];
    const float* fc1w = (const float*)d_in[4];
    const float* fc1b = (const float*)d_in[5];
    float* out = (float*)d_out;

    float* ws   = (float*)d_ws;
    float* h0G  = ws;               // 4096
    float* h1G  = ws + 4096;        // 4096
    float* h2G  = ws + 8192;        // 4096
    float* dstG = ws + 12288;       // 4096
    float* srcG = ws + 16384;       // 4096
    float* xG   = ws + 20480;       // 4*4096*3 = 49152

    prep_kernel<<<N_ENT / 256, 256, 0, stream>>>(emb, W, a, h0G, h1G, h2G, dstG, srcG);
    gat_row_kernel<<<512, 1024, 0, stream>>>(adj, h0G, h1G, h2G, dstG, srcG, xG);
    fc_kernel<<<100, 256, 0, stream>>>(xG, fc1w, fc1b, out);
}

// Round 5
// 383.064 us; speedup vs baseline: 1.4158x; 1.0019x over previous
//
#include <hip/hip_runtime.h>
#include <math.h>

#define N_ENT 4096
#define BATCH 4
#define NHID  3
#define EMB   64
#define ALPHA 0.2f
#define MASK_FILL 9e-15f
#define LOG2E 1.4426950408889634f
#define MASKP (MASK_FILL * LOG2E)

#if defined(__has_builtin)
#  if __has_builtin(__builtin_amdgcn_exp2f)
#    define EXP2F(x) __builtin_amdgcn_exp2f(x)
#  else
#    define EXP2F(x) exp2f(x)
#  endif
#else
#  define EXP2F(x) exp2f(x)
#endif

// ---------------------------------------------------------------------------
// Kernel 1: h = ent_emb @ W; dst' = (h@a[3:])*log2e; src' = (h@a[:3])*log2e.
// ---------------------------------------------------------------------------
__global__ __launch_bounds__(256) void prep_kernel(
    const float* __restrict__ emb, const float* __restrict__ W,
    const float* __restrict__ a,
    float* __restrict__ h0G, float* __restrict__ h1G, float* __restrict__ h2G,
    float* __restrict__ dstG, float* __restrict__ srcG)
{
    int j = blockIdx.x * 256 + threadIdx.x;
    if (j >= N_ENT) return;
    const float* er = emb + (size_t)j * EMB;
    float h0 = 0.f, h1 = 0.f, h2 = 0.f;
    #pragma unroll
    for (int e = 0; e < EMB; ++e) {
        float v = er[e];
        h0 += v * W[e * 3 + 0];
        h1 += v * W[e * 3 + 1];
        h2 += v * W[e * 3 + 2];
    }
    h0G[j] = h0; h1G[j] = h1; h2G[j] = h2;
    srcG[j] = (h0 * a[0] + h1 * a[1] + h2 * a[2]) * LOG2E;
    dstG[j] = (h0 * a[3] + h1 * a[4] + h2 * a[5]) * LOG2E;
}

// ---------------------------------------------------------------------------
// Kernel 2: fixed-reference softmax (M >= all logits via block max of dst),
// TWO rows per wave in one chunk loop:
//   - LDS reads (dst,h0,h1,h2) shared by both rows -> LDS port time halved
//   - depth-2 register prefetch x 2 rows = 4 outstanding global loads/wave
//     (hides ~500cy L3 latency; R4's unroll-1 had ~1 outstanding -> 70% stall)
// __launch_bounds__(1024,4): <=128 VGPR, no spill risk (~80 live), 16 wv/CU.
// ---------------------------------------------------------------------------
__global__ __launch_bounds__(1024, 4) void gat_row_kernel(
    const int* __restrict__ adj,
    const float* __restrict__ h0G, const float* __restrict__ h1G,
    const float* __restrict__ h2G, const float* __restrict__ dstG,
    const float* __restrict__ srcG, float* __restrict__ xG)
{
    __shared__ float dstL[N_ENT];   // SoA: b128 reads bank-clean
    __shared__ float h0L[N_ENT];
    __shared__ float h1L[N_ENT];
    __shared__ float h2L[N_ENT];
    __shared__ float maxdL[16];

    int tid  = threadIdx.x;
    int lane = tid & 63;
    int wid  = tid >> 6;            // 0..15

    float md = -3.4e38f;
    #pragma unroll
    for (int t = tid; t < N_ENT; t += 1024) {
        float dv = dstG[t];
        dstL[t] = dv;
        md = fmaxf(md, dv);
        h0L[t] = h0G[t];
        h1L[t] = h1G[t];
        h2L[t] = h2G[t];
    }
    #pragma unroll
    for (int off = 32; off; off >>= 1) md = fmaxf(md, __shfl_xor(md, off, 64));
    if (lane == 0) maxdL[wid] = md;
    __syncthreads();
    float maxd = maxdL[0];
    #pragma unroll
    for (int t = 1; t < 16; ++t) maxd = fmaxf(maxd, maxdL[t]);

    int gw   = blockIdx.x * 16 + wid;     // 0..8191
    int rowA = gw * 2;                    // 0..16382
    int rowB = rowA + 1;

    float srcA = srcG[rowA & (N_ENT - 1)];
    float srcB = srcG[rowB & (N_ENT - 1)];
    float tA = srcA + maxd;
    float MA = fmaxf(fmaxf(tA, ALPHA * tA), (float)MASKP);
    float sA0 = srcA - MA, sA1 = ALPHA * srcA - MA;
    float CA  = EXP2F((float)MASKP - MA);
    float tB = srcB + maxd;
    float MB = fmaxf(fmaxf(tB, ALPHA * tB), (float)MASKP);
    float sB0 = srcB - MB, sB1 = ALPHA * srcB - MB;
    float CB  = EXP2F((float)MASKP - MB);

    const int4* pA = (const int4*)(adj + (size_t)rowA * N_ENT);
    const int4* pB = (const int4*)(adj + (size_t)rowB * N_ENT);

    // depth-2 prefetch pipeline
    int4 c0A = pA[lane],      c0B = pB[lane];
    int4 c1A = pA[64 + lane], c1B = pB[64 + lane];

    float lA = 0.f, nA0 = 0.f, nA1 = 0.f, nA2 = 0.f;
    float lB = 0.f, nB0 = 0.f, nB1 = 0.f, nB2 = 0.f;

    #pragma unroll 1
    for (int c = 0; c < 16; ++c) {
        int4 avA = c0A, avB = c0B;
        c0A = c1A; c0B = c1B;
        int cn = c + 2;
        if (cn < 16) {                     // wave-uniform branch
            c1A = pA[cn * 64 + lane];
            c1B = pB[cn * 64 + lane];
        }

        int jb = (c * 64 + lane) * 4;
        float4 d4 = *(const float4*)&dstL[jb];
        float4 a0 = *(const float4*)&h0L[jb];
        float4 a1 = *(const float4*)&h1L[jb];
        float4 a2 = *(const float4*)&h2L[jb];

        // ---- row A ----
        {
            float g0 = EXP2F(fmaxf(sA0 + d4.x, fmaf(ALPHA, d4.x, sA1)));
            float g1 = EXP2F(fmaxf(sA0 + d4.y, fmaf(ALPHA, d4.y, sA1)));
            float g2 = EXP2F(fmaxf(sA0 + d4.z, fmaf(ALPHA, d4.z, sA1)));
            float g3 = EXP2F(fmaxf(sA0 + d4.w, fmaf(ALPHA, d4.w, sA1)));
            float w0 = avA.x > 0 ? g0 : CA;
            float w1 = avA.y > 0 ? g1 : CA;
            float w2 = avA.z > 0 ? g2 : CA;
            float w3 = avA.w > 0 ? g3 : CA;
            lA += (w0 + w1) + (w2 + w3);
            nA0 = fmaf(w0, a0.x, fmaf(w1, a0.y, fmaf(w2, a0.z, fmaf(w3, a0.w, nA0))));
            nA1 = fmaf(w0, a1.x, fmaf(w1, a1.y, fmaf(w2, a1.z, fmaf(w3, a1.w, nA1))));
            nA2 = fmaf(w0, a2.x, fmaf(w1, a2.y, fmaf(w2, a2.z, fmaf(w3, a2.w, nA2))));
        }
        // ---- row B (reuses d4/a0/a1/a2) ----
        {
            float g0 = EXP2F(fmaxf(sB0 + d4.x, fmaf(ALPHA, d4.x, sB1)));
            float g1 = EXP2F(fmaxf(sB0 + d4.y, fmaf(ALPHA, d4.y, sB1)));
            float g2 = EXP2F(fmaxf(sB0 + d4.z, fmaf(ALPHA, d4.z, sB1)));
            float g3 = EXP2F(fmaxf(sB0 + d4.w, fmaf(ALPHA, d4.w, sB1)));
            float w0 = avB.x > 0 ? g0 : CB;
            float w1 = avB.y > 0 ? g1 : CB;
            float w2 = avB.z > 0 ? g2 : CB;
            float w3 = avB.w > 0 ? g3 : CB;
            lB += (w0 + w1) + (w2 + w3);
            nB0 = fmaf(w0, a0.x, fmaf(w1, a0.y, fmaf(w2, a0.z, fmaf(w3, a0.w, nB0))));
            nB1 = fmaf(w0, a1.x, fmaf(w1, a1.y, fmaf(w2, a1.z, fmaf(w3, a1.w, nB1))));
            nB2 = fmaf(w0, a2.x, fmaf(w1, a2.y, fmaf(w2, a2.z, fmaf(w3, a2.w, nB2))));
        }
    }

    #pragma unroll
    for (int off = 32; off; off >>= 1) {
        lA  += __shfl_xor(lA,  off, 64);
        nA0 += __shfl_xor(nA0, off, 64);
        nA1 += __shfl_xor(nA1, off, 64);
        nA2 += __shfl_xor(nA2, off, 64);
        lB  += __shfl_xor(lB,  off, 64);
        nB0 += __shfl_xor(nB0, off, 64);
        nB1 += __shfl_xor(nB1, off, 64);
        nB2 += __shfl_xor(nB2, off, 64);
    }

    if (lane == 0) {
        float* xp = xG + (size_t)rowA * 3;   // 6 contiguous floats (rows A,B)
        float invA = 1.f / lA;
        float h0 = nA0 * invA, h1 = nA1 * invA, h2 = nA2 * invA;
        xp[0] = h0 > 0.f ? h0 : expm1f(h0);
        xp[1] = h1 > 0.f ? h1 : expm1f(h1);
        xp[2] = h2 > 0.f ? h2 : expm1f(h2);
        float invB = 1.f / lB;
        float g0 = nB0 * invB, g1 = nB1 * invB, g2 = nB2 * invB;
        xp[3] = g0 > 0.f ? g0 : expm1f(g0);
        xp[4] = g1 > 0.f ? g1 : expm1f(g1);
        xp[5] = g2 > 0.f ? g2 : expm1f(g2);
    }
}

// ---------------------------------------------------------------------------
// Kernel 3: out[b,k] = x[b,:] . fc1_w[k,:] + fc1_b[k].
// ---------------------------------------------------------------------------
__global__ __launch_bounds__(256) void fc_kernel(
    const float* __restrict__ xG, const float* __restrict__ w,
    const float* __restrict__ bias, float* __restrict__ out)
{
    int k   = blockIdx.x;           // 0..99
    int tid = threadIdx.x;
    const float4* wr = (const float4*)(w + (size_t)k * (N_ENT * NHID));
    const float4* x0 = (const float4*)(xG + 0 * (N_ENT * NHID));
    const float4* x1 = (const float4*)(xG + 1 * (N_ENT * NHID));
    const float4* x2 = (const float4*)(xG + 2 * (N_ENT * NHID));
    const float4* x3 = (const float4*)(xG + 3 * (N_ENT * NHID));

    float acc0 = 0.f, acc1 = 0.f, acc2 = 0.f, acc3 = 0.f;
    for (int t = tid; t < (N_ENT * NHID / 4); t += 256) {
        float4 wv = wr[t];
        float4 xv;
        xv = x0[t]; acc0 += wv.x*xv.x + wv.y*xv.y + wv.z*xv.z + wv.w*xv.w;
        xv = x1[t]; acc1 += wv.x*xv.x + wv.y*xv.y + wv.z*xv.z + wv.w*xv.w;
        xv = x2[t]; acc2 += wv.x*xv.x + wv.y*xv.y + wv.z*xv.z + wv.w*xv.w;
        xv = x3[t]; acc3 += wv.x*xv.x + wv.y*xv.y + wv.z*xv.z + wv.w*xv.w;
    }

    #pragma unroll
    for (int off = 32; off; off >>= 1) {
        acc0 += __shfl_xor(acc0, off, 64);
        acc1 += __shfl_xor(acc1, off, 64);
        acc2 += __shfl_xor(acc2, off, 64);
        acc3 += __shfl_xor(acc3, off, 64);
    }

    __shared__ float red[4][4];
    int lane = tid & 63, wv_ = tid >> 6;
    if (lane == 0) {
        red[wv_][0] = acc0; red[wv_][1] = acc1;
        red[wv_][2] = acc2; red[wv_][3] = acc3;
    }
    __syncthreads();
    if (tid < 4) {
        float s = red[0][tid] + red[1][tid] + red[2][tid] + red[3][tid] + bias[k];
        out[tid * 100 + k] = s;
    }
}

// ---------------------------------------------------------------------------
extern "C" void kernel_launch(void* const* d_in, const int* in_sizes, int n_in,
                              void* d_out, int out_size, void* d_ws, size_t ws_size,
                              hipStream_t stream)
{
    const int*   adj  = (const int*)d_in[0];
    const float* emb  = (const float*)d_in[1];
    const float* W    = (const float*)d_in[2];
    const float* a    = (const float*)d_in[3];
    const float* fc1w = (const float*)d_in[4];
    const float* fc1b = (const float*)d_in[5];
    float* out = (float*)d_out;

    float* ws   = (float*)d_ws;
    float* h0G  = ws;               // 4096
    float* h1G  = ws + 4096;        // 4096
    float* h2G  = ws + 8192;        // 4096
    float* dstG = ws + 12288;       // 4096
    float* srcG = ws + 16384;       // 4096
    float* xG   = ws + 20480;       // 4*4096*3 = 49152

    prep_kernel<<<N_ENT / 256, 256, 0, stream>>>(emb, W, a, h0G, h1G, h2G, dstG, srcG);
    gat_row_kernel<<<512, 1024, 0, stream>>>(adj, h0G, h1G, h2G, dstG, srcG, xG);
    fc_kernel<<<100, 256, 0, stream>>>(xG, fc1w, fc1b, out);
}